// Round 4
// baseline (177.425 us; speedup 1.0000x reference)
//
#include <hip/hip_runtime.h>

typedef __attribute__((ext_vector_type(8))) short s8bf;   // 8 x bf16 (as i16)
typedef __attribute__((ext_vector_type(4))) float f4;
typedef __attribute__((ext_vector_type(2))) unsigned u2;

#define HQ 32
#define HK 8
#define DH 128
#define LK 1024   // keys per (b,g)

static __device__ __forceinline__ unsigned pkbf(float a, float b) {
  // round-half-up bf16 pair pack: a -> low16, b -> high16
  unsigned ua = __builtin_bit_cast(unsigned, a) + 0x8000u;
  unsigned ub = __builtin_bit_cast(unsigned, b) + 0x8000u;
  return (ua >> 16) | (ub & 0xffff0000u);
}

static __device__ __forceinline__ void dma16(const short* g, short* l) {
  __builtin_amdgcn_global_load_lds((const __attribute__((address_space(1))) void*)g,
                                   (__attribute__((address_space(3))) void*)l, 16, 0, 0);
}

union frag_u { s8bf v; unsigned u[4]; };

// ---------------- prepass: K -> bf16 [bg][key][d]; V -> bf16^T [bg][d][key] ----------------
__global__ void prep_kernel(const float* __restrict__ kg, const float* __restrict__ vg,
                            short* __restrict__ kbf, short* __restrict__ vtb) {
  const int blk = blockIdx.x;
  if (blk < 512) {
    // K convert, dest-linear (both sides coalesced)
    const int tid0 = blk * 256 + threadIdx.x;
#pragma unroll
    for (int i = 0; i < 4; ++i) {
      int e = tid0 + i * 131072;          // 524288 d-quads total
      int d = (e & 31) * 4;
      int key = (e >> 5) & 1023;
      int bg = e >> 15;
      int b = bg >> 3, g = bg & 7;
      f4 x = *(const f4*)(kg + (((size_t)(b * 1024 + key) * HK + g) * DH + d));
      u2 w; w[0] = pkbf(x[0], x[1]); w[1] = pkbf(x[2], x[3]);
      *(u2*)(kbf + ((size_t)bg * 1024 + key) * DH + d) = w;
    }
  } else {
    // V transpose: one 64-key x 128-d tile per block
    __shared__ short T[64 * 130];
    const int t = blk - 512;              // 0..255
    const int bg = t >> 4, kt = t & 15;
    const int b = bg >> 3, g = bg & 7;
#pragma unroll
    for (int i = 0; i < 8; ++i) {
      int e = threadIdx.x * 4 + i * 1024; // 8192 elems = 64x128
      int key = e >> 7, d = e & 127;
      f4 x = *(const f4*)(vg + (((size_t)(b * 1024 + kt * 64 + key) * HK + g) * DH + d));
      u2 w; w[0] = pkbf(x[0], x[1]); w[1] = pkbf(x[2], x[3]);
      *(u2*)&T[key * 130 + d] = w;
    }
    __syncthreads();
#pragma unroll
    for (int i = 0; i < 16; ++i) {
      int j = threadIdx.x + i * 256;      // 4096 u32 writes
      int r = j >> 5;                     // d row 0..127
      int kgp = (j & 31) * 2;             // key pair
      unsigned lo = (unsigned short)T[kgp * 130 + r];
      unsigned hi = (unsigned short)T[(kgp + 1) * 130 + r];
      *(unsigned*)(vtb + ((size_t)bg * DH + r) * LK + kt * 64 + kgp) = lo | (hi << 16);
    }
  }
}

// ---------------- main flash kernel ----------------
__launch_bounds__(512, 4)
__global__ void fa_main(const float* __restrict__ qg, const short* __restrict__ kbf,
                        const short* __restrict__ vtb, float* __restrict__ out) {
  __shared__ short KL[2][8192];   // two 16 KB K tiles, fragment-major: f*512 + lane*8 shorts

  const int id   = blockIdx.x;             // 0..511
  const int slot = id >> 3;                // 0..63
  const int bg   = (id & 7) + 8 * (slot & 1);   // XCD-local kv-head pair
  const int rem  = slot >> 1;              // 0..31
  const int h4   = rem & 3;
  const int p    = rem >> 2;               // 0..7 -> q-tile pair (p, 15-p)
  const int b    = bg >> 3, g = bg & 7;
  const int h    = g * 4 + h4;

  const int tid  = threadIdx.x;
  const int wave = tid >> 6, lane = tid & 63;
  const int l16  = lane & 15, quad = lane >> 4;
  const int qt   = (wave >> 2) ? (15 - p) : p;
  const int qtmax = 15 - p;
  const int qlocal = (wave & 3) * 16 + l16;
  const int q0   = qt * 64;
  const int seq0 = b * 1024;

  const short* kb = kbf + (size_t)bg * LK * DH;
  const short* vt = vtb + (size_t)bg * DH * LK;

  // ---- Q fragment (f32 global -> bf16 regs; once per wave)
  const float* qp = qg + ((size_t)(seq0 + q0 + qlocal) * HQ + h) * DH;
  s8bf qf[4];
#pragma unroll
  for (int dk = 0; dk < 4; ++dk) {
    const float* ptr = qp + dk * 32 + quad * 8;
    f4 a = *(const f4*)(ptr);
    f4 c = *(const f4*)(ptr + 4);
    frag_u tt;
    tt.u[0] = pkbf(a[0], a[1]); tt.u[1] = pkbf(a[2], a[3]);
    tt.u[2] = pkbf(c[0], c[1]); tt.u[3] = pkbf(c[2], c[3]);
    qf[dk] = tt.v;
  }

  // ---- DMA lane offsets for this wave's two K fragments
  const int f0 = wave * 2;
  int goff[2];
#pragma unroll
  for (int ff = 0; ff < 2; ++ff) {
    int f = f0 + ff;                      // frag id: ct=f>>2, dk=f&3
    goff[ff] = ((f >> 2) * 16 + l16) * DH + (f & 3) * 32 + quad * 8;
  }
  // initial DMA: K tile 0 -> KL[0]
#pragma unroll
  for (int ff = 0; ff < 2; ++ff)
    dma16(kb + goff[ff], &KL[0][(f0 + ff) * 512 + lane * 8]);

  float m_ = -1e30f, l_ = 0.0f;
  f4 oacc[8];
#pragma unroll
  for (int dt = 0; dt < 8; ++dt) oacc[dt] = (f4)(0.0f);

  const float qsc = 0.08838834764831845f * 1.4426950408889634f;  // 1/sqrt(128)*log2e

  for (int kt = 0; kt <= qtmax; ++kt) {
    __syncthreads();   // waits own DMA (vmcnt drain), then all waves' DMA complete

    // ---- issue next tile's DMA into the other buffer (overlaps compute)
    if (kt < qtmax) {
      const short* kbn = kb + (size_t)(kt + 1) * 64 * DH;
#pragma unroll
      for (int ff = 0; ff < 2; ++ff)
        dma16(kbn + goff[ff], &KL[(kt + 1) & 1][(f0 + ff) * 512 + lane * 8]);
    }

    if (kt <= qt) {
      const short* KC = KL[kt & 1];

      // ---- S^T = K Q^T : conflict-free lane-linear b128 fragment reads
      f4 sacc[4];
#pragma unroll
      for (int ct = 0; ct < 4; ++ct) sacc[ct] = (f4)(0.0f);
#pragma unroll
      for (int dk = 0; dk < 4; ++dk) {
#pragma unroll
        for (int ct = 0; ct < 4; ++ct) {
          s8bf kf = *(const s8bf*)&KC[(ct * 4 + dk) * 512 + lane * 8];
          sacc[ct] = __builtin_amdgcn_mfma_f32_16x16x32_bf16(kf, qf[dk], sacc[ct], 0, 0, 0);
        }
      }

      // ---- scale (exp2 domain) + causal mask on diagonal tile
      if (kt == qt) {
#pragma unroll
        for (int ct = 0; ct < 4; ++ct)
#pragma unroll
          for (int i = 0; i < 4; ++i) {
            int key = ct * 16 + quad * 4 + i;
            float sv = sacc[ct][i] * qsc;
            sacc[ct][i] = (key > qlocal) ? -1e30f : sv;
          }
      } else {
#pragma unroll
        for (int ct = 0; ct < 4; ++ct)
#pragma unroll
          for (int i = 0; i < 4; ++i) sacc[ct][i] *= qsc;
      }

      // ---- online softmax: in-lane tree + xor16/xor32
      float r01 = fmaxf(fmaxf(sacc[0][0], sacc[0][1]), fmaxf(sacc[0][2], sacc[0][3]));
      float r23 = fmaxf(fmaxf(sacc[1][0], sacc[1][1]), fmaxf(sacc[1][2], sacc[1][3]));
      float r45 = fmaxf(fmaxf(sacc[2][0], sacc[2][1]), fmaxf(sacc[2][2], sacc[2][3]));
      float r67 = fmaxf(fmaxf(sacc[3][0], sacc[3][1]), fmaxf(sacc[3][2], sacc[3][3]));
      float r = fmaxf(fmaxf(r01, r23), fmaxf(r45, r67));
      r = fmaxf(r, __shfl_xor(r, 16));
      r = fmaxf(r, __shfl_xor(r, 32));
      float mn = fmaxf(m_, r);
      float alpha = exp2f(m_ - mn);
      m_ = mn;

      float rs = 0.0f;
#pragma unroll
      for (int ct = 0; ct < 4; ++ct)
#pragma unroll
        for (int i = 0; i < 4; ++i) {
          float pv = exp2f(sacc[ct][i] - mn);
          sacc[ct][i] = pv;
          rs += pv;
        }
      rs += __shfl_xor(rs, 16);
      rs += __shfl_xor(rs, 32);          // off the PV critical path
      l_ = l_ * alpha + rs;
#pragma unroll
      for (int dt = 0; dt < 8; ++dt) oacc[dt] *= alpha;

      // ---- pack P + in-register transpose to PV B-fragment
      unsigned pk[4][2];
#pragma unroll
      for (int ct = 0; ct < 4; ++ct) {
        pk[ct][0] = pkbf(sacc[ct][0], sacc[ct][1]);
        pk[ct][1] = pkbf(sacc[ct][2], sacc[ct][3]);
      }
      const int srcA = ((quad & 1) << 5) + l16;
      const int srcB = srcA + 16;
      const bool hi = (quad >> 1) != 0;

      // ---- O^T += V^T P^T, V-frags straight from global bf16 (L1-shared)
      const short* vbase = vt + kt * 64 + quad * 8;
#pragma unroll
      for (int ks = 0; ks < 2; ++ks) {
        frag_u fr;
#pragma unroll
        for (int w = 0; w < 2; ++w) {
          unsigned a0 = (unsigned)__shfl((int)pk[2 * ks][w], srcA);
          unsigned a1 = (unsigned)__shfl((int)pk[2 * ks + 1][w], srcA);
          fr.u[w] = hi ? a1 : a0;
          unsigned b0 = (unsigned)__shfl((int)pk[2 * ks][w], srcB);
          unsigned b1 = (unsigned)__shfl((int)pk[2 * ks + 1][w], srcB);
          fr.u[2 + w] = hi ? b1 : b0;
        }
#pragma unroll
        for (int dt = 0; dt < 8; ++dt) {
          s8bf vf = *(const s8bf*)&vbase[(size_t)(dt * 16 + l16) * LK + ks * 32];
          oacc[dt] = __builtin_amdgcn_mfma_f32_16x16x32_bf16(vf, fr.v, oacc[dt], 0, 0, 0);
        }
      }
    }
  }

  // ---- epilogue: lane (quad,l16) holds O[q=l16][d=dt*16+quad*4+i]
  float inv = 1.0f / l_;
  float* op = out + ((size_t)(seq0 + q0 + qlocal) * HQ + h) * DH;
#pragma unroll
  for (int dt = 0; dt < 8; ++dt) {
    f4 w;
    w[0] = oacc[dt][0] * inv; w[1] = oacc[dt][1] * inv;
    w[2] = oacc[dt][2] * inv; w[3] = oacc[dt][3] * inv;
    *(f4*)&op[dt * 16 + quad * 4] = w;
  }
}

extern "C" void kernel_launch(void* const* d_in, const int* in_sizes, int n_in,
                              void* d_out, int out_size, void* d_ws, size_t ws_size,
                              hipStream_t stream) {
  const float* q = (const float*)d_in[0];
  const float* k = (const float*)d_in[1];
  const float* v = (const float*)d_in[2];
  float* out = (float*)d_out;

  short* kbf = (short*)d_ws;                       // 16*1024*128 bf16 = 4 MB
  short* vtb = kbf + (size_t)16 * 1024 * 128;      // 4 MB more

  prep_kernel<<<dim3(768), 256, 0, stream>>>(k, v, kbf, vtb);
  fa_main<<<dim3(512), 512, 0, stream>>>(q, kbf, vtb, out);
}